// Round 23
// baseline (93.886 us; speedup 1.0000x reference)
//
#include <hip/hip_runtime.h>
#include <math.h>

// B=256, P=40, S=60, D=64. Round-23 = Round-20 (best: 69.9 us, VGPR 112,
// no spill) with ONE change: weight fragments read from GLOBAL (L2-hot,
// 40 KB read-only, replicated in every XCD's L2) instead of LDS.
// LDS drops 100 KB -> 60 KB (x-tiles only) => 2 WGs/CU co-resident
// = 16 waves/CU = 4 waves/SIMD, double R20's residency. Weight-load
// latency 120->200 cyc is covered by the doubled TLP. Also deletes the
// weight-staging loop and the only __syncthreads (barrier-free WG).
// R22 lesson folded in: x stays in LDS (reload-from-HBM cost 13 us).
//
// Register-chain trick: MFMA contraction is invariant to permuting the k-dim.
// C/D output holds the row-dim in-lane as {16mt+4g+j}; the next GEMM
// contracting that dim takes both operands by pure register reindexing:
//     frag[nt][ks] = pk16( acc2[2ks][nb], acc2[2ks+1][nb] )
// map pi(ks,i,g)=16*(2ks+(i>>2))+4g+(i&3). W1/W2 pre-permuted to pi-layout.
//
// Layout facts (cdna4 guide, measured m89/m91):
//   C/D: lane holds col=lane&15, rows 16mt+4(lane>>4)+j
//   A/B: row(col)=lane&15, kappa = 32ks+8(lane>>4)+i

typedef _Float16 half8 __attribute__((ext_vector_type(8)));
typedef __fp16 fp16x2 __attribute__((ext_vector_type(2)));
typedef float f4 __attribute__((ext_vector_type(4)));

#define MFMA16(a, b, c) __builtin_amdgcn_mfma_f32_16x16x32_f16((a), (b), (c), 0, 0, 0)

__global__ __launch_bounds__(256) void prep_weights(
    const float* __restrict__ Wq, const float* __restrict__ Wk,
    const float* __restrict__ Wv, const float* __restrict__ W1,
    const float* __restrict__ W2, _Float16* __restrict__ wsH) {
    int idx = blockIdx.x * 256 + threadIdx.x;  // 0..20479
    int m = idx >> 12, r = idx & 4095;
    const float* src = (m == 0) ? Wq : (m == 1) ? Wk : (m == 2) ? Wv
                        : (m == 3) ? W1 : W2;
    float v;
    if (m < 3) {
        v = src[r];  // natural row-major [e][d]
    } else {
        // pi-permuted: position (e, kappa) holds W[e][ d=16*(2ks+(i>>2))+4g+(i&3) ]
        int e = r >> 6, kp = r & 63;
        int ks = kp >> 5, gg = (kp >> 3) & 3, i = kp & 7;
        int d = 16 * (2 * ks + (i >> 2)) + 4 * gg + (i & 3);
        v = src[e * 64 + d];
    }
    wsH[idx] = (_Float16)v;
}

// Packed f32x4 + f32x4 -> half8 via v_cvt_pkrtz_f16_f32 (4 insts).
__device__ __forceinline__ half8 pk8(f4 a, f4 b) {
    union { half8 h; fp16x2 p[4]; } u;
    u.p[0] = __builtin_amdgcn_cvt_pkrtz(a[0], a[1]);
    u.p[1] = __builtin_amdgcn_cvt_pkrtz(a[2], a[3]);
    u.p[2] = __builtin_amdgcn_cvt_pkrtz(b[0], b[1]);
    u.p[3] = __builtin_amdgcn_cvt_pkrtz(b[2], b[3]);
    return u.h;
}

// Half-width GEMM into acc2[4][2]: output cols nt in {2h, 2h+1}.
// AEXPR uses (t, ks); BEXPR uses (nt, ks); CEXPR uses (mt, nb, nt).
#define GEMM_H(AEXPR, BEXPR, CEXPR)                                          \
    do {                                                                     \
        _Pragma("unroll")                                                    \
        for (int ks = 0; ks < 2; ++ks) {                                     \
            half8 afr[4], bfr[2];                                            \
            _Pragma("unroll")                                                \
            for (int t = 0; t < 4; ++t) afr[t] = (AEXPR);                    \
            _Pragma("unroll")                                                \
            for (int nb = 0; nb < 2; ++nb) {                                 \
                const int nt = 2 * h + nb; (void)nt;                         \
                bfr[nb] = (BEXPR);                                           \
            }                                                                \
            _Pragma("unroll")                                                \
            for (int mt = 0; mt < 4; ++mt)                                   \
                _Pragma("unroll")                                            \
                for (int nb = 0; nb < 2; ++nb) {                             \
                    const int nt = 2 * h + nb; (void)nt;                     \
                    acc2[mt][nb] = MFMA16(afr[mt], bfr[nb],                  \
                                          ks == 0 ? (CEXPR) : acc2[mt][nb]); \
                }                                                            \
        }                                                                    \
    } while (0)

// acc2 -> pi-layout frags for this half (dst[2h+nb][ks]).
#define MKFR_H(dst, RELU)                                                    \
    do {                                                                     \
        _Pragma("unroll")                                                    \
        for (int nb = 0; nb < 2; ++nb)                                       \
            _Pragma("unroll")                                                \
            for (int ks = 0; ks < 2; ++ks) {                                 \
                f4 a_ = acc2[2 * ks][nb], b_ = acc2[2 * ks + 1][nb];         \
                if (RELU) {                                                  \
                    _Pragma("unroll")                                        \
                    for (int j = 0; j < 4; ++j) {                            \
                        a_[j] = fmaxf(a_[j], 0.f);                           \
                        b_[j] = fmaxf(b_[j], 0.f);                           \
                    }                                                        \
                }                                                            \
                dst[2 * h + nb][ks] = pk8(a_, b_);                           \
            }                                                                \
    } while (0)

// Weight fragment from GLOBAL (L2-hot prepped table, natural layout):
// element (row = 16*RB+lo, kappa = 32ks+8g) of matrix widx.
#define WFRAG(widx, RB) (*(const half8*)&wH[(widx) * 4096 + (16 * (RB) + lo) * 64 + \
                                            32 * ks + 8 * g])

// x fragment from LDS (rows >= 60 -> zero; constant-folds for RB < 3).
#define XFRAG(RB) __extension__({                                            \
    int row_ = 16 * (RB) + lo;                                               \
    int rowc_ = row_ < 60 ? row_ : 48;                                       \
    half8 v_ = *(const half8*)&wlds[xbase + rowc_ * 64 +                     \
                                    ((32 * ks + 8 * g) ^ ((lo & 7) << 3))];  \
    if (row_ >= 60) { half8 z_ = {}; v_ = z_; }                              \
    v_; })

__global__ __launch_bounds__(512, 1) void fused_f16(
    const float* __restrict__ x, const _Float16* __restrict__ wH,
    const float* __restrict__ bq, const float* __restrict__ bk,
    const float* __restrict__ bv, const float* __restrict__ b1,
    const float* __restrict__ b2, const float* __restrict__ W3,
    const float* __restrict__ b3, float* __restrict__ out) {
    // 8 x-tiles (60x64 f16, swizzled) = 61440 B -> 2 WGs/CU.
    __shared__ __align__(16) _Float16 wlds[30720];

    const int tid = threadIdx.x;
    const int l = tid & 63;           // lane
    const int w = tid >> 6;           // wave 0..7 (one part each)
    const int lo = l & 15, g = l >> 4;

    const int part = blockIdx.x * 8 + w;   // one part per wave
    const int xbase = w * 3840;            // this wave's x tile (halves)
    const float* __restrict__ xp = x + (size_t)part * (60 * 64);

    // ---- stage this part's x into LDS (f16, swizzled). Own region, same-wave
    // in-order LDS -> NO barrier anywhere in the kernel.
    #pragma unroll
    for (int m = 0; m < 8; ++m) {
        int chunk = m * 64 + l;               // 480 16B-chunks (60 rows x 8)
        if (chunk < 480) {
            int row = chunk >> 3, c = chunk & 7;
            const float* p = xp + row * 64 + c * 8;
            half8 hv = pk8(*(const f4*)p, *(const f4*)(p + 4));
            *(half8*)&wlds[xbase + row * 64 + ((c * 8) ^ ((row & 7) << 3))] = hv;
        }
    }

    const f4 zc = {0.f, 0.f, 0.f, 0.f};
    f4 acc2[4][2];
    f4 brow[4];
    half8 qf[4][2], kf[4][2], vf[4][2], pf[4][2], wtf[4][2], h1f[4][2];

    // ---- qT = Wq * xT + bq
    #pragma unroll
    for (int mt = 0; mt < 4; ++mt) brow[mt] = *(const f4*)&bq[16 * mt + 4 * g];
    #pragma unroll
    for (int h = 0; h < 2; ++h) {
        GEMM_H(WFRAG(0, t), XFRAG(nt), brow[mt]);
        MKFR_H(qf, false);
    }

    // ---- kT = Wk * xT + bk
    #pragma unroll
    for (int mt = 0; mt < 4; ++mt) brow[mt] = *(const f4*)&bk[16 * mt + 4 * g];
    #pragma unroll
    for (int h = 0; h < 2; ++h) {
        GEMM_H(WFRAG(1, t), XFRAG(nt), brow[mt]);
        MKFR_H(kf, false);
    }

    // ---- scoresT + softmax + P, per half (A = kf regs, B = qf half)
    #pragma unroll
    for (int h = 0; h < 2; ++h) {
        GEMM_H(kf[t][ks], qf[nt][ks], zc);
        #pragma unroll
        for (int nb = 0; nb < 2; ++nb) {
            float sum = 0.f;
            #pragma unroll
            for (int mt = 0; mt < 4; ++mt)
                #pragma unroll
                for (int j = 0; j < 4; ++j) {
                    float e = (mt == 3 && g == 3)
                                  ? 0.f
                                  : exp2f(acc2[mt][nb][j] * 0.1803368801111137f);
                    acc2[mt][nb][j] = e;
                    sum += e;
                }
            sum += __shfl_xor(sum, 16);
            sum += __shfl_xor(sum, 32);
            float inv = 1.f / sum;
            #pragma unroll
            for (int mt = 0; mt < 4; ++mt)
                #pragma unroll
                for (int j = 0; j < 4; ++j) acc2[mt][nb][j] *= inv;
        }
        MKFR_H(pf, false);
    }
    // qf, kf dead here.

    // ---- v = x * WvT + bv (col-splat C-in), per half
    #pragma unroll
    for (int h = 0; h < 2; ++h) {
        float bc[2];
        #pragma unroll
        for (int nb = 0; nb < 2; ++nb) bc[nb] = bv[16 * (2 * h + nb) + lo];
        GEMM_H(XFRAG(t), WFRAG(2, nt),
               ((f4){bc[nb], bc[nb], bc[nb], bc[nb]}));
        MKFR_H(vf, false);
    }

    // ---- weightedT = vT * P, per half (A = vf regs, B = pf half)
    #pragma unroll
    for (int h = 0; h < 2; ++h) {
        GEMM_H(vf[t][ks], pf[nt][ks], zc);
        MKFR_H(wtf, false);
    }
    // vf, pf dead here.

    // ---- h1T = relu(W1 * weightedT + b1)   (W1 pi-permuted)
    #pragma unroll
    for (int mt = 0; mt < 4; ++mt) brow[mt] = *(const f4*)&b1[16 * mt + 4 * g];
    #pragma unroll
    for (int h = 0; h < 2; ++h) {
        GEMM_H(WFRAG(3, t), wtf[nt][ks], brow[mt]);
        MKFR_H(h1f, true);
    }

    // ---- h2T = relu(W2 * h1T + b2), head folded per half on f32 acc
    #pragma unroll
    for (int mt = 0; mt < 4; ++mt) brow[mt] = *(const f4*)&b2[16 * mt + 4 * g];
    f4 w3r[4];
    #pragma unroll
    for (int mt = 0; mt < 4; ++mt) w3r[mt] = *(const f4*)&W3[16 * mt + 4 * g];
    float b3v = b3[0];
    #pragma unroll
    for (int h = 0; h < 2; ++h) {
        GEMM_H(WFRAG(4, t), h1f[nt][ks], brow[mt]);
        #pragma unroll
        for (int nb = 0; nb < 2; ++nb) {
            float sres = 0.f;
            #pragma unroll
            for (int mt = 0; mt < 4; ++mt)
                #pragma unroll
                for (int j = 0; j < 4; ++j)
                    sres += fmaxf(acc2[mt][nb][j], 0.f) * w3r[mt][j];
            sres += __shfl_xor(sres, 16);
            sres += __shfl_xor(sres, 32);
            if (g == 0) {
                int s = 16 * (2 * h + nb) + lo;
                if (s < 60) out[(size_t)part * 60 + s] = sres + b3v;
            }
        }
    }
}

extern "C" void kernel_launch(void* const* d_in, const int* in_sizes, int n_in,
                              void* d_out, int out_size, void* d_ws, size_t ws_size,
                              hipStream_t stream) {
    const float* x  = (const float*)d_in[0];
    const float* Wq = (const float*)d_in[1];
    const float* bq = (const float*)d_in[2];
    const float* Wk = (const float*)d_in[3];
    const float* bk = (const float*)d_in[4];
    const float* Wv = (const float*)d_in[5];
    const float* bv = (const float*)d_in[6];
    const float* W1 = (const float*)d_in[7];
    const float* b1 = (const float*)d_in[8];
    const float* W2 = (const float*)d_in[9];
    const float* b2 = (const float*)d_in[10];
    const float* W3 = (const float*)d_in[11];
    const float* b3 = (const float*)d_in[12];
    _Float16* wsH = (_Float16*)d_ws;  // 5 * 4096 halves = 40 KB

    prep_weights<<<80, 256, 0, stream>>>(Wq, Wk, Wv, W1, W2, wsH);
    // 1280 WGs x 512 thr = 8 waves/WG, one part per wave; x tiles in LDS
    // (60 KB -> 2 WGs/CU = 16 waves/CU); weights from L2; barrier-free.
    fused_f16<<<1280, 512, 0, stream>>>(x, wsH, bq, bk, bv, b1, b2, W3, b3,
                                        (float*)d_out);
}

// Round 24
// 85.240 us; speedup vs baseline: 1.1014x; 1.1014x over previous
//
#include <hip/hip_runtime.h>
#include <math.h>

// B=256, P=40, S=60, D=64. Round-24 = Round-20 body (best: 69.9 us, VGPR 112,
// x-tiles + weights in LDS, half-width GEMMs, no spill) launched COOPERATIVELY:
// 256 WGs x 512 thr = exactly 1 WG/CU guaranteed co-resident -> 8 waves/CU
// flat (vs ~6.1 average for normal launches; R11/R20/R22/R23 all show the
// dispatcher pins ~6.6 waves/CU regardless of static headroom). Each wave
// loops over 5 parts (2048 waves x 5 = 10240); sched_barrier(0) at loop top
// pins back-edge hoisting (R14-verified). Weights staged once per 5 parts.
// Correctness does NOT depend on co-residency (no grid sync) - only speed.
//
// Register-chain trick: MFMA contraction is invariant to permuting the k-dim.
// C/D output holds the row-dim in-lane as {16mt+4g+j}; the next GEMM
// contracting that dim takes both operands by pure register reindexing:
//     frag[nt][ks] = pk16( acc2[2ks][nb], acc2[2ks+1][nb] )
// map pi(ks,i,g)=16*(2ks+(i>>2))+4g+(i&3). W1/W2 pre-permuted to pi-layout.
//
// Layout facts (cdna4 guide, measured m89/m91):
//   C/D: lane holds col=lane&15, rows 16mt+4(lane>>4)+j
//   A/B: row(col)=lane&15, kappa = 32ks+8(lane>>4)+i

typedef _Float16 half8 __attribute__((ext_vector_type(8)));
typedef __fp16 fp16x2 __attribute__((ext_vector_type(2)));
typedef float f4 __attribute__((ext_vector_type(4)));

#define MFMA16(a, b, c) __builtin_amdgcn_mfma_f32_16x16x32_f16((a), (b), (c), 0, 0, 0)

__global__ __launch_bounds__(256) void prep_weights(
    const float* __restrict__ Wq, const float* __restrict__ Wk,
    const float* __restrict__ Wv, const float* __restrict__ W1,
    const float* __restrict__ W2, _Float16* __restrict__ wsH) {
    int idx = blockIdx.x * 256 + threadIdx.x;  // 0..20479
    int m = idx >> 12, r = idx & 4095;
    const float* src = (m == 0) ? Wq : (m == 1) ? Wk : (m == 2) ? Wv
                        : (m == 3) ? W1 : W2;
    float v;
    if (m < 3) {
        v = src[r];  // natural row-major [e][d]
    } else {
        // pi-permuted: position (e, kappa) holds W[e][ d=16*(2ks+(i>>2))+4g+(i&3) ]
        int e = r >> 6, kp = r & 63;
        int ks = kp >> 5, gg = (kp >> 3) & 3, i = kp & 7;
        int d = 16 * (2 * ks + (i >> 2)) + 4 * gg + (i & 3);
        v = src[e * 64 + d];
    }
    wsH[idx] = (_Float16)v;
}

// Packed f32x4 + f32x4 -> half8 via v_cvt_pkrtz_f16_f32 (4 insts).
__device__ __forceinline__ half8 pk8(f4 a, f4 b) {
    union { half8 h; fp16x2 p[4]; } u;
    u.p[0] = __builtin_amdgcn_cvt_pkrtz(a[0], a[1]);
    u.p[1] = __builtin_amdgcn_cvt_pkrtz(a[2], a[3]);
    u.p[2] = __builtin_amdgcn_cvt_pkrtz(b[0], b[1]);
    u.p[3] = __builtin_amdgcn_cvt_pkrtz(b[2], b[3]);
    return u.h;
}

// Half-width GEMM into acc2[4][2]: output cols nt in {2h, 2h+1}.
// AEXPR uses (t, ks); BEXPR uses (nt, ks); CEXPR uses (mt, nb, nt).
#define GEMM_H(AEXPR, BEXPR, CEXPR)                                          \
    do {                                                                     \
        _Pragma("unroll")                                                    \
        for (int ks = 0; ks < 2; ++ks) {                                     \
            half8 afr[4], bfr[2];                                            \
            _Pragma("unroll")                                                \
            for (int t = 0; t < 4; ++t) afr[t] = (AEXPR);                    \
            _Pragma("unroll")                                                \
            for (int nb = 0; nb < 2; ++nb) {                                 \
                const int nt = 2 * h + nb; (void)nt;                         \
                bfr[nb] = (BEXPR);                                           \
            }                                                                \
            _Pragma("unroll")                                                \
            for (int mt = 0; mt < 4; ++mt)                                   \
                _Pragma("unroll")                                            \
                for (int nb = 0; nb < 2; ++nb) {                             \
                    const int nt = 2 * h + nb; (void)nt;                     \
                    acc2[mt][nb] = MFMA16(afr[mt], bfr[nb],                  \
                                          ks == 0 ? (CEXPR) : acc2[mt][nb]); \
                }                                                            \
        }                                                                    \
    } while (0)

// acc2 -> pi-layout frags for this half (dst[2h+nb][ks]).
#define MKFR_H(dst, RELU)                                                    \
    do {                                                                     \
        _Pragma("unroll")                                                    \
        for (int nb = 0; nb < 2; ++nb)                                       \
            _Pragma("unroll")                                                \
            for (int ks = 0; ks < 2; ++ks) {                                 \
                f4 a_ = acc2[2 * ks][nb], b_ = acc2[2 * ks + 1][nb];         \
                if (RELU) {                                                  \
                    _Pragma("unroll")                                        \
                    for (int j = 0; j < 4; ++j) {                            \
                        a_[j] = fmaxf(a_[j], 0.f);                           \
                        b_[j] = fmaxf(b_[j], 0.f);                           \
                    }                                                        \
                }                                                            \
                dst[2 * h + nb][ks] = pk8(a_, b_);                           \
            }                                                                \
    } while (0)

// Weight fragment from LDS: matrix widx, row-block RB (row = 16*RB+lo),
// kappa chunk (32ks+8g), XOR-swizzled by (lo&7)<<3 halves.
#define WFRAG(widx, RB) (*(const half8*)&wlds[(widx) * 4096 + (16 * (RB) + lo) * 64 + \
                                              ((32 * ks + 8 * g) ^ ((lo & 7) << 3))])

// x fragment from LDS (rows >= 60 -> zero; constant-folds for RB < 3).
#define XFRAG(RB) __extension__({                                            \
    int row_ = 16 * (RB) + lo;                                               \
    int rowc_ = row_ < 60 ? row_ : 48;                                       \
    half8 v_ = *(const half8*)&wlds[xbase + rowc_ * 64 +                     \
                                    ((32 * ks + 8 * g) ^ ((lo & 7) << 3))];  \
    if (row_ >= 60) { half8 z_ = {}; v_ = z_; }                              \
    v_; })

__global__ __launch_bounds__(512, 1) void fused_f16(
    const float* __restrict__ x, const _Float16* __restrict__ wH,
    const float* __restrict__ bq, const float* __restrict__ bk,
    const float* __restrict__ bv, const float* __restrict__ b1,
    const float* __restrict__ b2, const float* __restrict__ W3,
    const float* __restrict__ b3, float* __restrict__ out) {
    // 40 KB weights + 8 x-tiles (60x64 f16, swizzled) = 102400 B = 100 KB.
    __shared__ __align__(16) _Float16 wlds[51200];

    const int tid = threadIdx.x;
    const int l = tid & 63;           // lane
    const int w = tid >> 6;           // wave 0..7
    const int lo = l & 15, g = l >> 4;

    // ---- cooperative weight load global->LDS with write-side swizzle.
    #pragma unroll
    for (int rep = 0; rep < 5; ++rep) {
        int chunk = rep * 512 + tid;          // 0..2559
        int widx = chunk >> 9;
        int rem = chunk & 511;
        int row = rem >> 3, c = rem & 7;
        *(half8*)&wlds[widx * 4096 + row * 64 + ((c * 8) ^ ((row & 7) << 3))] =
            *(const half8*)&wH[widx * 4096 + row * 64 + c * 8];
    }
    __syncthreads();  // once; waves independent afterwards

    const int gid = blockIdx.x * 8 + w;    // 0..2047
    const int xbase = 20480 + w * 3840;    // this wave's x tile (halves)

    #pragma unroll 1
    for (int it = 0; it < 5; ++it) {
        // Pin the back-edge: no hoisting of next iteration's loads (R14).
        __builtin_amdgcn_sched_barrier(0);

        const int part = gid + it * 2048;  // 2048 waves x 5 = 10240 parts
        const float* __restrict__ xp = x + (size_t)part * (60 * 64);

        // ---- stage this part's x into LDS (f16, swizzled). Own region;
        // same-wave in-order LDS: prior iter's reads precede these writes.
        #pragma unroll
        for (int m = 0; m < 8; ++m) {
            int chunk = m * 64 + l;           // 480 16B-chunks (60 rows x 8)
            if (chunk < 480) {
                int row = chunk >> 3, c = chunk & 7;
                const float* p = xp + row * 64 + c * 8;
                half8 hv = pk8(*(const f4*)p, *(const f4*)(p + 4));
                *(half8*)&wlds[xbase + row * 64 + ((c * 8) ^ ((row & 7) << 3))] = hv;
            }
        }

        const f4 zc = {0.f, 0.f, 0.f, 0.f};
        f4 acc2[4][2];
        f4 brow[4];
        half8 qf[4][2], kf[4][2], vf[4][2], pf[4][2], wtf[4][2], h1f[4][2];

        // ---- qT = Wq * xT + bq
        #pragma unroll
        for (int mt = 0; mt < 4; ++mt) brow[mt] = *(const f4*)&bq[16 * mt + 4 * g];
        #pragma unroll
        for (int h = 0; h < 2; ++h) {
            GEMM_H(WFRAG(0, t), XFRAG(nt), brow[mt]);
            MKFR_H(qf, false);
        }

        // ---- kT = Wk * xT + bk
        #pragma unroll
        for (int mt = 0; mt < 4; ++mt) brow[mt] = *(const f4*)&bk[16 * mt + 4 * g];
        #pragma unroll
        for (int h = 0; h < 2; ++h) {
            GEMM_H(WFRAG(1, t), XFRAG(nt), brow[mt]);
            MKFR_H(kf, false);
        }

        // ---- scoresT + softmax + P, per half (A = kf regs, B = qf half)
        #pragma unroll
        for (int h = 0; h < 2; ++h) {
            GEMM_H(kf[t][ks], qf[nt][ks], zc);
            #pragma unroll
            for (int nb = 0; nb < 2; ++nb) {
                float sum = 0.f;
                #pragma unroll
                for (int mt = 0; mt < 4; ++mt)
                    #pragma unroll
                    for (int j = 0; j < 4; ++j) {
                        float e = (mt == 3 && g == 3)
                                      ? 0.f
                                      : exp2f(acc2[mt][nb][j] *
                                              0.1803368801111137f);
                        acc2[mt][nb][j] = e;
                        sum += e;
                    }
                sum += __shfl_xor(sum, 16);
                sum += __shfl_xor(sum, 32);
                float inv = 1.f / sum;
                #pragma unroll
                for (int mt = 0; mt < 4; ++mt)
                    #pragma unroll
                    for (int j = 0; j < 4; ++j) acc2[mt][nb][j] *= inv;
            }
            MKFR_H(pf, false);
        }
        // qf, kf dead here.

        // ---- v = x * WvT + bv (col-splat C-in), per half
        #pragma unroll
        for (int h = 0; h < 2; ++h) {
            float bc[2];
            #pragma unroll
            for (int nb = 0; nb < 2; ++nb) bc[nb] = bv[16 * (2 * h + nb) + lo];
            GEMM_H(XFRAG(t), WFRAG(2, nt),
                   ((f4){bc[nb], bc[nb], bc[nb], bc[nb]}));
            MKFR_H(vf, false);
        }

        // ---- weightedT = vT * P, per half (A = vf regs, B = pf half)
        #pragma unroll
        for (int h = 0; h < 2; ++h) {
            GEMM_H(vf[t][ks], pf[nt][ks], zc);
            MKFR_H(wtf, false);
        }
        // vf, pf dead here.

        // ---- h1T = relu(W1 * weightedT + b1)   (W1 pi-permuted)
        #pragma unroll
        for (int mt = 0; mt < 4; ++mt) brow[mt] = *(const f4*)&b1[16 * mt + 4 * g];
        #pragma unroll
        for (int h = 0; h < 2; ++h) {
            GEMM_H(WFRAG(3, t), wtf[nt][ks], brow[mt]);
            MKFR_H(h1f, true);
        }

        // ---- h2T = relu(W2 * h1T + b2), head folded per half on f32 acc
        #pragma unroll
        for (int mt = 0; mt < 4; ++mt) brow[mt] = *(const f4*)&b2[16 * mt + 4 * g];
        f4 w3r[4];
        #pragma unroll
        for (int mt = 0; mt < 4; ++mt) w3r[mt] = *(const f4*)&W3[16 * mt + 4 * g];
        float b3v = b3[0];
        #pragma unroll
        for (int h = 0; h < 2; ++h) {
            GEMM_H(WFRAG(4, t), h1f[nt][ks], brow[mt]);
            #pragma unroll
            for (int nb = 0; nb < 2; ++nb) {
                float sres = 0.f;
                #pragma unroll
                for (int mt = 0; mt < 4; ++mt)
                    #pragma unroll
                    for (int j = 0; j < 4; ++j)
                        sres += fmaxf(acc2[mt][nb][j], 0.f) * w3r[mt][j];
                sres += __shfl_xor(sres, 16);
                sres += __shfl_xor(sres, 32);
                if (g == 0) {
                    int s = 16 * (2 * h + nb) + lo;
                    if (s < 60) out[(size_t)part * 60 + s] = sres + b3v;
                }
            }
        }
    }
}

extern "C" void kernel_launch(void* const* d_in, const int* in_sizes, int n_in,
                              void* d_out, int out_size, void* d_ws, size_t ws_size,
                              hipStream_t stream) {
    const float* x  = (const float*)d_in[0];
    const float* Wq = (const float*)d_in[1];
    const float* bq = (const float*)d_in[2];
    const float* Wk = (const float*)d_in[3];
    const float* bk = (const float*)d_in[4];
    const float* Wv = (const float*)d_in[5];
    const float* bv = (const float*)d_in[6];
    const float* W1 = (const float*)d_in[7];
    const float* b1 = (const float*)d_in[8];
    const float* W2 = (const float*)d_in[9];
    const float* b2 = (const float*)d_in[10];
    const float* W3 = (const float*)d_in[11];
    const float* b3 = (const float*)d_in[12];
    _Float16* wsH = (_Float16*)d_ws;  // 5 * 4096 halves = 40 KB

    prep_weights<<<80, 256, 0, stream>>>(Wq, Wk, Wv, W1, W2, wsH);

    // Cooperative launch: 256 WGs x 512 thr = exactly 1 WG/CU co-resident,
    // 8 waves/CU flat; each wave loops over 5 parts.
    const _Float16* wHc = wsH;
    float* outp = (float*)d_out;
    void* args[] = {(void*)&x,  (void*)&wHc, (void*)&bq, (void*)&bk,
                    (void*)&bv, (void*)&b1,  (void*)&b2, (void*)&W3,
                    (void*)&b3, (void*)&outp};
    hipLaunchCooperativeKernel((const void*)fused_f16, dim3(256), dim3(512),
                               args, 0, stream);
}

// Round 25
// 69.536 us; speedup vs baseline: 1.3502x; 1.2258x over previous
//
#include <hip/hip_runtime.h>
#include <math.h>

// B=256, P=40, S=60, D=64. Round-25 = Round-20 (best, 69.9 us, no spill)
// + within-stage A-fragment reuse. Finding: residency is pinned ~6.5-8
// waves/CU regardless of structure (R20-R24); the lever is the per-wave
// serial chain, which is dominated by ~104 ds_read_b128/part (~120 cyc
// serial links). In every W-stage the A-operand frags are IDENTICAL for
// both output halves; preloading them (32 transient VGPRs) and running
// both halves from regs cuts reads to ~64/part while keeping every
// stage's liveness <= 128 (the 512-thr allocator budget):
//   k-stage afr+qf+kf+acc=128 | scores qf+kf+pf+acc=128 | v xfr+pf+vf+acc=128
//
// Register-chain trick: MFMA contraction is invariant to permuting the k-dim.
// C/D output holds the row-dim in-lane as {16mt+4g+j}; the next GEMM
// contracting that dim takes both operands by pure register reindexing:
//     frag[nt][ks] = pk16( acc2[2ks][nb], acc2[2ks+1][nb] )
// map pi(ks,i,g)=16*(2ks+(i>>2))+4g+(i&3). W1/W2 pre-permuted to pi-layout.
//
// Layout facts (cdna4 guide, measured m89/m91):
//   C/D: lane holds col=lane&15, rows 16mt+4(lane>>4)+j
//   A/B: row(col)=lane&15, kappa = 32ks+8(lane>>4)+i

typedef _Float16 half8 __attribute__((ext_vector_type(8)));
typedef __fp16 fp16x2 __attribute__((ext_vector_type(2)));
typedef float f4 __attribute__((ext_vector_type(4)));

#define MFMA16(a, b, c) __builtin_amdgcn_mfma_f32_16x16x32_f16((a), (b), (c), 0, 0, 0)

__global__ __launch_bounds__(256) void prep_weights(
    const float* __restrict__ Wq, const float* __restrict__ Wk,
    const float* __restrict__ Wv, const float* __restrict__ W1,
    const float* __restrict__ W2, _Float16* __restrict__ wsH) {
    int idx = blockIdx.x * 256 + threadIdx.x;  // 0..20479
    int m = idx >> 12, r = idx & 4095;
    const float* src = (m == 0) ? Wq : (m == 1) ? Wk : (m == 2) ? Wv
                        : (m == 3) ? W1 : W2;
    float v;
    if (m < 3) {
        v = src[r];  // natural row-major [e][d]
    } else {
        // pi-permuted: position (e, kappa) holds W[e][ d=16*(2ks+(i>>2))+4g+(i&3) ]
        int e = r >> 6, kp = r & 63;
        int ks = kp >> 5, gg = (kp >> 3) & 3, i = kp & 7;
        int d = 16 * (2 * ks + (i >> 2)) + 4 * gg + (i & 3);
        v = src[e * 64 + d];
    }
    wsH[idx] = (_Float16)v;
}

// Packed f32x4 + f32x4 -> half8 via v_cvt_pkrtz_f16_f32 (4 insts).
__device__ __forceinline__ half8 pk8(f4 a, f4 b) {
    union { half8 h; fp16x2 p[4]; } u;
    u.p[0] = __builtin_amdgcn_cvt_pkrtz(a[0], a[1]);
    u.p[1] = __builtin_amdgcn_cvt_pkrtz(a[2], a[3]);
    u.p[2] = __builtin_amdgcn_cvt_pkrtz(b[0], b[1]);
    u.p[3] = __builtin_amdgcn_cvt_pkrtz(b[2], b[3]);
    return u.h;
}

// acc2 -> pi-layout frags for this half (dst[2h+nb][ks]).
#define MKFR_H(dst, RELU)                                                    \
    do {                                                                     \
        _Pragma("unroll")                                                    \
        for (int nb = 0; nb < 2; ++nb)                                       \
            _Pragma("unroll")                                                \
            for (int ks = 0; ks < 2; ++ks) {                                 \
                f4 a_ = acc2[2 * ks][nb], b_ = acc2[2 * ks + 1][nb];         \
                if (RELU) {                                                  \
                    _Pragma("unroll")                                        \
                    for (int j = 0; j < 4; ++j) {                            \
                        a_[j] = fmaxf(a_[j], 0.f);                           \
                        b_[j] = fmaxf(b_[j], 0.f);                           \
                    }                                                        \
                }                                                            \
                dst[2 * h + nb][ks] = pk8(a_, b_);                           \
            }                                                                \
    } while (0)

// Half-width GEMM into acc2[4][2] with A already in regs (AREG indexed
// [mt][ks]); B loaded per (h, ks). Used for scores/PV (A = kf/vf).
#define GEMM_R(AREG, BEXPR, CEXPR)                                           \
    do {                                                                     \
        _Pragma("unroll")                                                    \
        for (int ks = 0; ks < 2; ++ks) {                                     \
            half8 bfr[2];                                                    \
            _Pragma("unroll")                                                \
            for (int nb = 0; nb < 2; ++nb) {                                 \
                const int nt = 2 * h + nb; (void)nt;                         \
                bfr[nb] = (BEXPR);                                           \
            }                                                                \
            _Pragma("unroll")                                                \
            for (int mt = 0; mt < 4; ++mt)                                   \
                _Pragma("unroll")                                            \
                for (int nb = 0; nb < 2; ++nb) {                             \
                    const int nt = 2 * h + nb; (void)nt;                     \
                    acc2[mt][nb] = MFMA16(AREG[mt][ks], bfr[nb],             \
                                          ks == 0 ? (CEXPR) : acc2[mt][nb]); \
                }                                                            \
        }                                                                    \
    } while (0)

// Full stage with A-frag preload shared across BOTH halves (the read-count
// lever): 8 A-reads + 8 B-reads per stage instead of 16 + 8.
// AEXPR uses (t, ks); BEXPR uses (nt, ks); CEXPR uses (mt, nb, nt).
#define STAGE_A(AEXPR, BEXPR, CEXPR, DST, RELU)                              \
    do {                                                                     \
        half8 afr2[4][2];                                                    \
        _Pragma("unroll")                                                    \
        for (int t = 0; t < 4; ++t)                                          \
            _Pragma("unroll")                                                \
            for (int ks = 0; ks < 2; ++ks) afr2[t][ks] = (AEXPR);            \
        _Pragma("unroll")                                                    \
        for (int h = 0; h < 2; ++h) {                                        \
            GEMM_R(afr2, BEXPR, CEXPR);                                      \
            MKFR_H(DST, RELU);                                               \
        }                                                                    \
    } while (0)

// Weight fragment from LDS: matrix widx, row-block RB (row = 16*RB+lo),
// kappa chunk (32ks+8g), XOR-swizzled by (lo&7)<<3 halves.
#define WFRAG(widx, RB) (*(const half8*)&wlds[(widx) * 4096 + (16 * (RB) + lo) * 64 + \
                                              ((32 * ks + 8 * g) ^ ((lo & 7) << 3))])

// x fragment from LDS (rows >= 60 -> zero; constant-folds for RB < 3).
#define XFRAG(RB) __extension__({                                            \
    int row_ = 16 * (RB) + lo;                                               \
    int rowc_ = row_ < 60 ? row_ : 48;                                       \
    half8 v_ = *(const half8*)&wlds[xbase + rowc_ * 64 +                     \
                                    ((32 * ks + 8 * g) ^ ((lo & 7) << 3))];  \
    if (row_ >= 60) { half8 z_ = {}; v_ = z_; }                              \
    v_; })

__global__ __launch_bounds__(512, 1) void fused_f16(
    const float* __restrict__ x, const _Float16* __restrict__ wH,
    const float* __restrict__ bq, const float* __restrict__ bk,
    const float* __restrict__ bv, const float* __restrict__ b1,
    const float* __restrict__ b2, const float* __restrict__ W3,
    const float* __restrict__ b3, float* __restrict__ out) {
    // 40 KB weights + 8 x-tiles (60x64 f16, swizzled) = 102400 B = 100 KB.
    __shared__ __align__(16) _Float16 wlds[51200];

    const int tid = threadIdx.x;
    const int l = tid & 63;           // lane
    const int w = tid >> 6;           // wave 0..7 (one part each)
    const int lo = l & 15, g = l >> 4;

    // ---- cooperative weight load global->LDS with write-side swizzle.
    #pragma unroll
    for (int rep = 0; rep < 5; ++rep) {
        int chunk = rep * 512 + tid;          // 0..2559
        int widx = chunk >> 9;
        int rem = chunk & 511;
        int row = rem >> 3, c = rem & 7;
        *(half8*)&wlds[widx * 4096 + row * 64 + ((c * 8) ^ ((row & 7) << 3))] =
            *(const half8*)&wH[widx * 4096 + row * 64 + c * 8];
    }
    __syncthreads();  // weights visible to all; waves independent afterwards

    const int part = blockIdx.x * 8 + w;   // one part per wave
    const int xbase = 20480 + w * 3840;    // this wave's x tile (halves)
    const float* __restrict__ xp = x + (size_t)part * (60 * 64);

    // ---- stage this part's x into LDS (f16, swizzled). Own region, same-wave
    // in-order LDS -> no barrier needed.
    #pragma unroll
    for (int m = 0; m < 8; ++m) {
        int chunk = m * 64 + l;               // 480 16B-chunks (60 rows x 8)
        if (chunk < 480) {
            int row = chunk >> 3, c = chunk & 7;
            const float* p = xp + row * 64 + c * 8;
            half8 hv = pk8(*(const f4*)p, *(const f4*)(p + 4));
            *(half8*)&wlds[xbase + row * 64 + ((c * 8) ^ ((row & 7) << 3))] = hv;
        }
    }

    const f4 zc = {0.f, 0.f, 0.f, 0.f};
    f4 acc2[4][2];
    f4 brow[4];
    half8 qf[4][2], kf[4][2], vf[4][2], pf[4][2], wtf[4][2], h1f[4][2];

    // ---- qT = Wq * xT + bq   (A = Wq preloaded, shared across halves)
    #pragma unroll
    for (int mt = 0; mt < 4; ++mt) brow[mt] = *(const f4*)&bq[16 * mt + 4 * g];
    STAGE_A(WFRAG(0, t), XFRAG(nt), brow[mt], qf, false);

    // ---- kT = Wk * xT + bk   (liveness peak: afr+qf+kf+acc = 128)
    #pragma unroll
    for (int mt = 0; mt < 4; ++mt) brow[mt] = *(const f4*)&bk[16 * mt + 4 * g];
    STAGE_A(WFRAG(1, t), XFRAG(nt), brow[mt], kf, false);

    // ---- scoresT + softmax + P, per half (A = kf regs, B = qf regs)
    #pragma unroll
    for (int h = 0; h < 2; ++h) {
        GEMM_R(kf, qf[nt][ks], zc);
        #pragma unroll
        for (int nb = 0; nb < 2; ++nb) {
            float sum = 0.f;
            #pragma unroll
            for (int mt = 0; mt < 4; ++mt)
                #pragma unroll
                for (int j = 0; j < 4; ++j) {
                    float e = (mt == 3 && g == 3)
                                  ? 0.f
                                  : exp2f(acc2[mt][nb][j] * 0.1803368801111137f);
                    acc2[mt][nb][j] = e;
                    sum += e;
                }
            sum += __shfl_xor(sum, 16);
            sum += __shfl_xor(sum, 32);
            float inv = 1.f / sum;
            #pragma unroll
            for (int mt = 0; mt < 4; ++mt)
                #pragma unroll
                for (int j = 0; j < 4; ++j) acc2[mt][nb][j] *= inv;
        }
        MKFR_H(pf, false);
    }
    // qf, kf dead here.

    // ---- v = x * WvT + bv   (A = x preloaded once, shared across halves)
    {
        float bcol[4];
        #pragma unroll
        for (int nt = 0; nt < 4; ++nt) bcol[nt] = bv[16 * nt + lo];
        STAGE_A(XFRAG(t), WFRAG(2, nt),
                ((f4){bcol[nt], bcol[nt], bcol[nt], bcol[nt]}), vf, false);
    }

    // ---- weightedT = vT * P, per half (A = vf regs, B = pf regs)
    #pragma unroll
    for (int h = 0; h < 2; ++h) {
        GEMM_R(vf, pf[nt][ks], zc);
        MKFR_H(wtf, false);
    }
    // vf, pf dead here.

    // ---- h1T = relu(W1 * weightedT + b1)   (W1 pi-permuted, A preloaded)
    #pragma unroll
    for (int mt = 0; mt < 4; ++mt) brow[mt] = *(const f4*)&b1[16 * mt + 4 * g];
    STAGE_A(WFRAG(3, t), wtf[nt][ks], brow[mt], h1f, true);

    // ---- h2T = relu(W2 * h1T + b2), head folded per half on f32 acc
    #pragma unroll
    for (int mt = 0; mt < 4; ++mt) brow[mt] = *(const f4*)&b2[16 * mt + 4 * g];
    f4 w3r[4];
    #pragma unroll
    for (int mt = 0; mt < 4; ++mt) w3r[mt] = *(const f4*)&W3[16 * mt + 4 * g];
    float b3v = b3[0];
    {
        half8 afr2[4][2];
        #pragma unroll
        for (int t = 0; t < 4; ++t)
            #pragma unroll
            for (int ks = 0; ks < 2; ++ks) afr2[t][ks] = WFRAG(4, t);
        #pragma unroll
        for (int h = 0; h < 2; ++h) {
            GEMM_R(afr2, h1f[nt][ks], brow[mt]);
            #pragma unroll
            for (int nb = 0; nb < 2; ++nb) {
                float sres = 0.f;
                #pragma unroll
                for (int mt = 0; mt < 4; ++mt)
                    #pragma unroll
                    for (int j = 0; j < 4; ++j)
                        sres += fmaxf(acc2[mt][nb][j], 0.f) * w3r[mt][j];
                sres += __shfl_xor(sres, 16);
                sres += __shfl_xor(sres, 32);
                if (g == 0) {
                    int s = 16 * (2 * h + nb) + lo;
                    if (s < 60) out[(size_t)part * 60 + s] = sres + b3v;
                }
            }
        }
    }
}

extern "C" void kernel_launch(void* const* d_in, const int* in_sizes, int n_in,
                              void* d_out, int out_size, void* d_ws, size_t ws_size,
                              hipStream_t stream) {
    const float* x  = (const float*)d_in[0];
    const float* Wq = (const float*)d_in[1];
    const float* bq = (const float*)d_in[2];
    const float* Wk = (const float*)d_in[3];
    const float* bk = (const float*)d_in[4];
    const float* Wv = (const float*)d_in[5];
    const float* bv = (const float*)d_in[6];
    const float* W1 = (const float*)d_in[7];
    const float* b1 = (const float*)d_in[8];
    const float* W2 = (const float*)d_in[9];
    const float* b2 = (const float*)d_in[10];
    const float* W3 = (const float*)d_in[11];
    const float* b3 = (const float*)d_in[12];
    _Float16* wsH = (_Float16*)d_ws;  // 5 * 4096 halves = 40 KB

    prep_weights<<<80, 256, 0, stream>>>(Wq, Wk, Wv, W1, W2, wsH);
    // 1280 WGs x 512 thr = 8 waves/WG, one part per wave; weights + per-wave
    // x tiles in LDS (100 KB); A-frag reuse cuts LDS reads 104 -> 64/part.
    fused_f16<<<1280, 512, 0, stream>>>(x, wsH, bq, bk, bv, b1, b2, W3, b3,
                                        (float*)d_out);
}